// Round 1
// baseline (3360.940 us; speedup 1.0000x reference)
//
#include <hip/hip_runtime.h>
#include <climits>

#define NU_ 80000
#define NS_ 20000
#define NM_ 30000
#define UIN_ (NU_ + NS_)
#define DD 128
#define BB 2048
#define LL 32

// ---------------------------------------------------------------------------
// Edge-parallel SpMM scatter: one wave per edge, lane i handles float2 at 2i.
// Source row gathered from xa (row < split) or xb (row - split).
// ---------------------------------------------------------------------------
__global__ void spmm_kernel(const int* __restrict__ rows, const int* __restrict__ cols,
                            const float* __restrict__ vals,
                            const float* __restrict__ xa, const float* __restrict__ xb,
                            int split, float* __restrict__ out, int E) {
    int gtid   = blockIdx.x * blockDim.x + threadIdx.x;
    int wave   = gtid >> 6;
    int lane   = threadIdx.x & 63;
    int nwaves = (gridDim.x * blockDim.x) >> 6;
    for (int e = wave; e < E; e += nwaves) {
        int   r = rows[e];
        int   c = cols[e];
        float v = vals[e];
        const float* x = (c < split) ? (xa + (size_t)c * DD)
                                     : (xb + (size_t)(c - split) * DD);
        float2 xv = *reinterpret_cast<const float2*>(x + lane * 2);
        float* o  = out + (size_t)r * DD + lane * 2;
        unsafeAtomicAdd(o,     v * xv.x);
        unsafeAtomicAdd(o + 1, v * xv.y);
    }
}

// m[row][*] *= d_inv[row], float4-vectorized
__global__ void scale_rows_kernel(float* __restrict__ m, const float* __restrict__ d_inv,
                                  size_t n4) {
    size_t stride = (size_t)gridDim.x * blockDim.x;
    for (size_t i = (size_t)blockIdx.x * blockDim.x + threadIdx.x; i < n4; i += stride) {
        size_t e   = i * 4;
        int    row = (int)(e >> 7);
        float  s   = d_inv[row];
        float4 v   = *reinterpret_cast<const float4*>(m + e);
        v.x *= s; v.y *= s; v.z *= s; v.w *= s;
        *reinterpret_cast<float4*>(m + e) = v;
    }
}

// h2 = (orig + h1 + h2) / 3, orig split across xa/xb tables
__global__ void combine3_kernel(const float* __restrict__ xa, const float* __restrict__ xb,
                                int split, const float* __restrict__ h1,
                                float* __restrict__ h2, size_t n4) {
    size_t stride = (size_t)gridDim.x * blockDim.x;
    const float inv3 = 1.0f / 3.0f;
    for (size_t i = (size_t)blockIdx.x * blockDim.x + threadIdx.x; i < n4; i += stride) {
        size_t e   = i * 4;
        int    row = (int)(e >> 7);
        int    col = (int)(e & 127);
        const float* orig = (row < split) ? (xa + (size_t)row * DD + col)
                                          : (xb + (size_t)(row - split) * DD + col);
        float4 o = *reinterpret_cast<const float4*>(orig);
        float4 a = *reinterpret_cast<const float4*>(h1 + e);
        float4 c = *reinterpret_cast<const float4*>(h2 + e);
        c.x = (o.x + a.x + c.x) * inv3;
        c.y = (o.y + a.y + c.y) * inv3;
        c.z = (o.z + a.z + c.z) * inv3;
        c.w = (o.w + a.w + c.w) * inv3;
        *reinterpret_cast<float4*>(h2 + e) = c;
    }
}

// ---------------------------------------------------------------------------
// Attention + prediction tail: one block (512 threads) per batch element.
// ---------------------------------------------------------------------------
__global__ __launch_bounds__(512) void attn_pred_kernel(
    const int* __restrict__ mashup_inputs, const int* __restrict__ service_inputs,
    const int* __restrict__ member_masked, const float* __restrict__ mask,
    const float* __restrict__ ui_final,    const float* __restrict__ mash_final,
    const float* __restrict__ att_w1, const float* __restrict__ att_b1,
    const float* __restrict__ att_w2, const float* __restrict__ att_b2,
    const float* __restrict__ pred_w1, const float* __restrict__ pred_b1,
    const float* __restrict__ pred_w2, const float* __restrict__ pred_b2,
    float* __restrict__ out)
{
    const int b   = blockIdx.x;
    const int tid = threadIdx.x;

    __shared__ float mem_lds[LL * 129];   // padded stride 129: breaks bank aliasing
    __shared__ float svc_lds[DD];
    __shared__ float w1_lds[2 * DD * 16];
    __shared__ float hdnw_lds[LL * 16];
    __shared__ float wt_lds[LL];
    __shared__ float new_lds[3 * DD];
    __shared__ float hp_lds[8];
    __shared__ int   midx[LL];

    if (tid < LL) midx[tid] = member_masked[b * LL + tid];
    for (int i = tid; i < 2 * DD * 16; i += 512) w1_lds[i] = att_w1[i];
    if (tid < DD) {
        int sidx = service_inputs[b];
        svc_lds[tid] = ui_final[(size_t)(NU_ + sidx) * DD + tid];
    }
    __syncthreads();

    for (int i = tid; i < LL * DD; i += 512) {
        int l = i >> 7, d = i & 127;
        mem_lds[l * 129 + d] = ui_final[(size_t)midx[l] * DD + d];
    }
    __syncthreads();

    // hidden layer: thread (l, j) computes hdn[l][j], fold att_w2 after relu
    {
        int l = tid >> 4, j = tid & 15;
        float acc = att_b1[j];
        const float* m = &mem_lds[l * 129];
        #pragma unroll 4
        for (int k = 0; k < DD; ++k) acc += m[k] * w1_lds[k * 16 + j];
        #pragma unroll 4
        for (int k = 0; k < DD; ++k) acc += svc_lds[k] * w1_lds[(DD + k) * 16 + j];
        acc = fmaxf(acc, 0.0f);
        hdnw_lds[l * 16 + j] = acc * att_w2[j];
    }
    __syncthreads();

    // scores + masked softmax on wave 0 (lanes 0..31 hold real rows)
    if (tid < 64) {
        float s = -3.0e38f;
        if (tid < LL) {
            s = att_b2[0];
            for (int j = 0; j < 16; ++j) s += hdnw_lds[tid * 16 + j];
            if (mask[b * LL + tid] > 0.0f) s = -1.0e9f;
        }
        float mx = s;
        for (int off = 16; off >= 1; off >>= 1) mx = fmaxf(mx, __shfl_xor(mx, off));
        float ex = (tid < LL) ? __expf(s - mx) : 0.0f;
        float sum = ex;
        for (int off = 16; off >= 1; off >>= 1) sum += __shfl_xor(sum, off);
        if (tid < LL) wt_lds[tid] = ex / sum;
    }
    __syncthreads();

    // g_att + mashup gather + elementwise, build new_emb(384) in LDS
    if (tid < DD) {
        float g = 0.0f;
        #pragma unroll 4
        for (int l = 0; l < LL; ++l) g += wt_lds[l] * mem_lds[l * 129 + tid];
        int   mi = mashup_inputs[b];
        float me = g + mash_final[(size_t)mi * DD + tid];
        float sv = svc_lds[tid];
        new_lds[tid]          = me * sv;
        new_lds[DD + tid]     = me;
        new_lds[2 * DD + tid] = sv;
    }
    __syncthreads();

    if (tid < 8) {
        float acc = pred_b1[tid];
        for (int k = 0; k < 3 * DD; ++k) acc += new_lds[k] * pred_w1[k * 8 + tid];
        acc = fmaxf(acc, 0.0f);
        hp_lds[tid] = acc * pred_w2[tid];
    }
    __syncthreads();

    if (tid == 0) {
        float z = pred_b2[0];
        for (int j = 0; j < 8; ++j) z += hp_lds[j];
        out[b] = 1.0f / (1.0f + __expf(-z));
    }
}

// ---------------------------------------------------------------------------
extern "C" void kernel_launch(void* const* d_in, const int* in_sizes, int n_in,
                              void* d_out, int out_size, void* d_ws, size_t ws_size,
                              hipStream_t stream) {
    const int*   mashup_inputs  = (const int*)  d_in[0];
    const int*   service_inputs = (const int*)  d_in[1];
    const int*   member_masked  = (const int*)  d_in[2];
    const float* mask           = (const float*)d_in[3];
    const int*   adj_rows       = (const int*)  d_in[4];
    const int*   adj_cols       = (const int*)  d_in[5];
    const float* adj_vals       = (const float*)d_in[6];
    const int*   A_rows         = (const int*)  d_in[7];
    const int*   A_cols         = (const int*)  d_in[8];
    const float* A_vals         = (const float*)d_in[9];
    const float* d_inv          = (const float*)d_in[10];
    const float* user_tbl       = (const float*)d_in[11];
    const float* service_tbl    = (const float*)d_in[12];
    const float* mashup_tbl     = (const float*)d_in[13];
    const float* att_w1         = (const float*)d_in[14];
    const float* att_b1         = (const float*)d_in[15];
    const float* att_w2         = (const float*)d_in[16];
    const float* att_b2         = (const float*)d_in[17];
    const float* pred_w1        = (const float*)d_in[18];
    const float* pred_b1        = (const float*)d_in[19];
    const float* pred_w2        = (const float*)d_in[20];
    const float* pred_b2        = (const float*)d_in[21];

    const int E_ui = in_sizes[4];
    const int E_mm = in_sizes[7];
    const int B    = in_sizes[0];

    float* ws = (float*)d_ws;
    float* h1 = ws;                              // 100000*128
    float* h2 = h1 + (size_t)UIN_ * DD;          // 100000*128 -> ui_final in place
    float* m1 = h2 + (size_t)UIN_ * DD;          // 30000*128
    float* m2 = m1 + (size_t)NM_ * DD;           // 30000*128 -> mash_final in place

    const size_t ui_bytes = (size_t)UIN_ * DD * sizeof(float);
    const size_t mm_bytes = (size_t)NM_ * DD * sizeof(float);

    // ---- user/service LightGCN propagation (2 layers) ----
    hipMemsetAsync(h1, 0, ui_bytes, stream);
    spmm_kernel<<<2048, 256, 0, stream>>>(adj_rows, adj_cols, adj_vals,
                                          user_tbl, service_tbl, NU_, h1, E_ui);
    hipMemsetAsync(h2, 0, ui_bytes, stream);
    spmm_kernel<<<2048, 256, 0, stream>>>(adj_rows, adj_cols, adj_vals,
                                          h1, h1, INT_MAX, h2, E_ui);
    combine3_kernel<<<2048, 256, 0, stream>>>(user_tbl, service_tbl, NU_,
                                              h1, h2, (size_t)UIN_ * DD / 4);

    // ---- mashup propagation (2 layers, with d_inv scaling) ----
    hipMemsetAsync(m1, 0, mm_bytes, stream);
    spmm_kernel<<<1024, 256, 0, stream>>>(A_rows, A_cols, A_vals,
                                          mashup_tbl, mashup_tbl, INT_MAX, m1, E_mm);
    scale_rows_kernel<<<1024, 256, 0, stream>>>(m1, d_inv, (size_t)NM_ * DD / 4);
    hipMemsetAsync(m2, 0, mm_bytes, stream);
    spmm_kernel<<<1024, 256, 0, stream>>>(A_rows, A_cols, A_vals,
                                          m1, m1, INT_MAX, m2, E_mm);
    scale_rows_kernel<<<1024, 256, 0, stream>>>(m2, d_inv, (size_t)NM_ * DD / 4);
    combine3_kernel<<<2048, 256, 0, stream>>>(mashup_tbl, mashup_tbl, INT_MAX,
                                              m1, m2, (size_t)NM_ * DD / 4);

    // ---- attention + prediction tail ----
    attn_pred_kernel<<<B, 512, 0, stream>>>(
        mashup_inputs, service_inputs, member_masked, mask,
        h2, m2,
        att_w1, att_b1, att_w2, att_b2,
        pred_w1, pred_b1, pred_w2, pred_b2,
        (float*)d_out);
}

// Round 2
// 904.880 us; speedup vs baseline: 3.7142x; 3.7142x over previous
//
#include <hip/hip_runtime.h>
#include <climits>

#define NU_ 80000
#define NS_ 20000
#define NM_ 30000
#define UIN_ (NU_ + NS_)
#define DD 128
#define LL 32

// ---------------------------------------------------------------------------
// CSR build: histogram -> single-block scan -> scatter into packed (col,val)
// ---------------------------------------------------------------------------
__global__ void hist_kernel(const int* __restrict__ rows, int* __restrict__ cnt, int E) {
    int stride = gridDim.x * blockDim.x;
    for (int i = blockIdx.x * blockDim.x + threadIdx.x; i < E; i += stride)
        atomicAdd(&cnt[rows[i]], 1);
}

// exclusive scan of cntcur[0..n) -> row_ptr[0..n]; cntcur overwritten with the
// same exclusive prefix (serves as the scatter cursor). Single 1024-thread block.
__global__ __launch_bounds__(1024) void scan_kernel(int* __restrict__ cntcur,
                                                    int* __restrict__ row_ptr, int n) {
    __shared__ int lds[1024];
    const int tid   = threadIdx.x;
    const int chunk = (n + 1023) >> 10;
    const int lo    = tid * chunk;
    const int hi    = min(lo + chunk, n);
    int s = 0;
    for (int i = lo; i < hi; ++i) s += cntcur[i];
    lds[tid] = s;
    __syncthreads();
    for (int off = 1; off < 1024; off <<= 1) {       // inclusive Hillis-Steele
        int v = (tid >= off) ? lds[tid - off] : 0;
        __syncthreads();
        lds[tid] += v;
        __syncthreads();
    }
    int run = (tid > 0) ? lds[tid - 1] : 0;
    for (int i = lo; i < hi; ++i) {
        int c = cntcur[i];
        row_ptr[i] = run;
        cntcur[i]  = run;
        run += c;
    }
    if (tid == 1023) row_ptr[n] = lds[1023];
}

__global__ void scatter_kernel(const int* __restrict__ rows, const int* __restrict__ cols,
                               const float* __restrict__ vals, int* __restrict__ cursor,
                               uint2* __restrict__ cv, int E) {
    int stride = gridDim.x * blockDim.x;
    for (int i = blockIdx.x * blockDim.x + threadIdx.x; i < E; i += stride) {
        int pos = atomicAdd(&cursor[rows[i]], 1);
        cv[pos] = make_uint2((unsigned)cols[i], __float_as_uint(vals[i]));
    }
}

// ---------------------------------------------------------------------------
// Pull SpMM: one wave per destination row, lane i owns float2 at dim 2i.
// MODE bit0: scale result by d_inv[row]. MODE bit1: out=(orig+hprev+res)/3.
// ---------------------------------------------------------------------------
template <int MODE>
__global__ __launch_bounds__(256) void pull_kernel(
    const int* __restrict__ row_ptr, const uint2* __restrict__ cv,
    const float* __restrict__ xa, const float* __restrict__ xb, int split,
    const float* __restrict__ d_inv,
    const float* __restrict__ oa, const float* __restrict__ ob, int osplit,
    const float* __restrict__ hprev,
    float* __restrict__ out, int n)
{
    const int wid  = (blockIdx.x * blockDim.x + threadIdx.x) >> 6;
    const int lane = threadIdx.x & 63;
    if (wid >= n) return;
    const int beg = row_ptr[wid];
    const int end = row_ptr[wid + 1];

    float2 acc0 = {0.f, 0.f}, acc1 = {0.f, 0.f};
    int e = beg;
    for (; e + 1 < end; e += 2) {
        uint2 p0 = cv[e];
        uint2 p1 = cv[e + 1];
        int   c0 = (int)p0.x;            float v0 = __uint_as_float(p0.y);
        int   c1 = (int)p1.x;            float v1 = __uint_as_float(p1.y);
        const float* x0 = (c0 < split) ? (xa + (size_t)c0 * DD)
                                       : (xb + (size_t)(c0 - split) * DD);
        const float* x1 = (c1 < split) ? (xa + (size_t)c1 * DD)
                                       : (xb + (size_t)(c1 - split) * DD);
        float2 g0 = *reinterpret_cast<const float2*>(x0 + lane * 2);
        float2 g1 = *reinterpret_cast<const float2*>(x1 + lane * 2);
        acc0.x += v0 * g0.x;  acc0.y += v0 * g0.y;
        acc1.x += v1 * g1.x;  acc1.y += v1 * g1.y;
    }
    if (e < end) {
        uint2 p0 = cv[e];
        int   c0 = (int)p0.x;            float v0 = __uint_as_float(p0.y);
        const float* x0 = (c0 < split) ? (xa + (size_t)c0 * DD)
                                       : (xb + (size_t)(c0 - split) * DD);
        float2 g0 = *reinterpret_cast<const float2*>(x0 + lane * 2);
        acc0.x += v0 * g0.x;  acc0.y += v0 * g0.y;
    }
    float2 acc = {acc0.x + acc1.x, acc0.y + acc1.y};

    if (MODE & 1) { float s = d_inv[wid]; acc.x *= s; acc.y *= s; }
    if (MODE & 2) {
        const float inv3 = 1.0f / 3.0f;
        const float* og = (wid < osplit) ? (oa + (size_t)wid * DD)
                                         : (ob + (size_t)(wid - osplit) * DD);
        float2 ov = *reinterpret_cast<const float2*>(og + lane * 2);
        float2 hv = *reinterpret_cast<const float2*>(hprev + (size_t)wid * DD + lane * 2);
        acc.x = (ov.x + hv.x + acc.x) * inv3;
        acc.y = (ov.y + hv.y + acc.y) * inv3;
    }
    *reinterpret_cast<float2*>(out + (size_t)wid * DD + lane * 2) = acc;
}

// ---------------------------------------------------------------------------
// Attention + prediction tail: one block (512 threads) per batch element.
// ---------------------------------------------------------------------------
__global__ __launch_bounds__(512) void attn_pred_kernel(
    const int* __restrict__ mashup_inputs, const int* __restrict__ service_inputs,
    const int* __restrict__ member_masked, const float* __restrict__ mask,
    const float* __restrict__ ui_final,    const float* __restrict__ mash_final,
    const float* __restrict__ att_w1, const float* __restrict__ att_b1,
    const float* __restrict__ att_w2, const float* __restrict__ att_b2,
    const float* __restrict__ pred_w1, const float* __restrict__ pred_b1,
    const float* __restrict__ pred_w2, const float* __restrict__ pred_b2,
    float* __restrict__ out)
{
    const int b   = blockIdx.x;
    const int tid = threadIdx.x;

    __shared__ float mem_lds[LL * 129];
    __shared__ float svc_lds[DD];
    __shared__ float w1_lds[2 * DD * 16];
    __shared__ float hdnw_lds[LL * 16];
    __shared__ float wt_lds[LL];
    __shared__ float new_lds[3 * DD];
    __shared__ float hp_lds[8];
    __shared__ int   midx[LL];

    if (tid < LL) midx[tid] = member_masked[b * LL + tid];
    for (int i = tid; i < 2 * DD * 16; i += 512) w1_lds[i] = att_w1[i];
    if (tid < DD) {
        int sidx = service_inputs[b];
        svc_lds[tid] = ui_final[(size_t)(NU_ + sidx) * DD + tid];
    }
    __syncthreads();

    for (int i = tid; i < LL * DD; i += 512) {
        int l = i >> 7, d = i & 127;
        mem_lds[l * 129 + d] = ui_final[(size_t)midx[l] * DD + d];
    }
    __syncthreads();

    {
        int l = tid >> 4, j = tid & 15;
        float acc = att_b1[j];
        const float* m = &mem_lds[l * 129];
        #pragma unroll 4
        for (int k = 0; k < DD; ++k) acc += m[k] * w1_lds[k * 16 + j];
        #pragma unroll 4
        for (int k = 0; k < DD; ++k) acc += svc_lds[k] * w1_lds[(DD + k) * 16 + j];
        acc = fmaxf(acc, 0.0f);
        hdnw_lds[l * 16 + j] = acc * att_w2[j];
    }
    __syncthreads();

    if (tid < 64) {
        float s = -3.0e38f;
        if (tid < LL) {
            s = att_b2[0];
            for (int j = 0; j < 16; ++j) s += hdnw_lds[tid * 16 + j];
            if (mask[b * LL + tid] > 0.0f) s = -1.0e9f;
        }
        float mx = s;
        for (int off = 16; off >= 1; off >>= 1) mx = fmaxf(mx, __shfl_xor(mx, off));
        float ex = (tid < LL) ? __expf(s - mx) : 0.0f;
        float sum = ex;
        for (int off = 16; off >= 1; off >>= 1) sum += __shfl_xor(sum, off);
        if (tid < LL) wt_lds[tid] = ex / sum;
    }
    __syncthreads();

    if (tid < DD) {
        float g = 0.0f;
        #pragma unroll 4
        for (int l = 0; l < LL; ++l) g += wt_lds[l] * mem_lds[l * 129 + tid];
        int   mi = mashup_inputs[b];
        float me = g + mash_final[(size_t)mi * DD + tid];
        float sv = svc_lds[tid];
        new_lds[tid]          = me * sv;
        new_lds[DD + tid]     = me;
        new_lds[2 * DD + tid] = sv;
    }
    __syncthreads();

    if (tid < 8) {
        float acc = pred_b1[tid];
        for (int k = 0; k < 3 * DD; ++k) acc += new_lds[k] * pred_w1[k * 8 + tid];
        acc = fmaxf(acc, 0.0f);
        hp_lds[tid] = acc * pred_w2[tid];
    }
    __syncthreads();

    if (tid == 0) {
        float z = pred_b2[0];
        for (int j = 0; j < 8; ++j) z += hp_lds[j];
        out[b] = 1.0f / (1.0f + __expf(-z));
    }
}

// ---------------------------------------------------------------------------
extern "C" void kernel_launch(void* const* d_in, const int* in_sizes, int n_in,
                              void* d_out, int out_size, void* d_ws, size_t ws_size,
                              hipStream_t stream) {
    const int*   mashup_inputs  = (const int*)  d_in[0];
    const int*   service_inputs = (const int*)  d_in[1];
    const int*   member_masked  = (const int*)  d_in[2];
    const float* mask           = (const float*)d_in[3];
    const int*   adj_rows       = (const int*)  d_in[4];
    const int*   adj_cols       = (const int*)  d_in[5];
    const float* adj_vals       = (const float*)d_in[6];
    const int*   A_rows         = (const int*)  d_in[7];
    const int*   A_cols         = (const int*)  d_in[8];
    const float* A_vals         = (const float*)d_in[9];
    const float* d_inv          = (const float*)d_in[10];
    const float* user_tbl       = (const float*)d_in[11];
    const float* service_tbl    = (const float*)d_in[12];
    const float* mashup_tbl     = (const float*)d_in[13];
    const float* att_w1         = (const float*)d_in[14];
    const float* att_b1         = (const float*)d_in[15];
    const float* att_w2         = (const float*)d_in[16];
    const float* att_b2         = (const float*)d_in[17];
    const float* pred_w1        = (const float*)d_in[18];
    const float* pred_b1        = (const float*)d_in[19];
    const float* pred_w2        = (const float*)d_in[20];
    const float* pred_b2        = (const float*)d_in[21];

    const int E_ui = in_sizes[4];
    const int E_mm = in_sizes[7];
    const int B    = in_sizes[0];

    // ---- workspace layout (floats) ----
    float* ws = (float*)d_ws;
    float* h1 = ws;                               // UIN*128
    float* h2 = h1 + (size_t)UIN_ * DD;           // UIN*128  (ui_final)
    float* m1 = h2 + (size_t)UIN_ * DD;           // NM*128
    float* m2 = m1 + (size_t)NM_ * DD;            // NM*128   (mash_final)
    uint2* ui_cv = (uint2*)(m2 + (size_t)NM_ * DD);           // E_ui
    uint2* mm_cv = ui_cv + E_ui;                              // E_mm
    int*   ui_rp = (int*)(mm_cv + E_mm);          // UIN+1
    int*   ui_cc = ui_rp + (UIN_ + 1);            // UIN+1
    int*   mm_rp = ui_cc + (UIN_ + 1);            // NM+1
    int*   mm_cc = mm_rp + (NM_ + 1);             // NM+1

    // ---- CSR build (both graphs) ----
    hipMemsetAsync(ui_cc, 0, (UIN_ + 1) * sizeof(int), stream);
    hipMemsetAsync(mm_cc, 0, (NM_ + 1) * sizeof(int), stream);
    hist_kernel<<<1024, 256, 0, stream>>>(adj_rows, ui_cc, E_ui);
    hist_kernel<<<512, 256, 0, stream>>>(A_rows, mm_cc, E_mm);
    scan_kernel<<<1, 1024, 0, stream>>>(ui_cc, ui_rp, UIN_);
    scan_kernel<<<1, 1024, 0, stream>>>(mm_cc, mm_rp, NM_);
    scatter_kernel<<<1024, 256, 0, stream>>>(adj_rows, adj_cols, adj_vals, ui_cc, ui_cv, E_ui);
    scatter_kernel<<<512, 256, 0, stream>>>(A_rows, A_cols, A_vals, mm_cc, mm_cv, E_mm);

    // ---- user/service LightGCN propagation (2 layers, pull) ----
    const int ui_blocks = (UIN_ + 3) / 4;   // 4 waves/block, 1 wave/row
    pull_kernel<0><<<ui_blocks, 256, 0, stream>>>(
        ui_rp, ui_cv, user_tbl, service_tbl, NU_,
        nullptr, nullptr, nullptr, 0, nullptr, h1, UIN_);
    pull_kernel<2><<<ui_blocks, 256, 0, stream>>>(
        ui_rp, ui_cv, h1, h1, INT_MAX,
        nullptr, user_tbl, service_tbl, NU_, h1, h2, UIN_);

    // ---- mashup propagation (2 layers, pull, d_inv fused) ----
    const int mm_blocks = (NM_ + 3) / 4;
    pull_kernel<1><<<mm_blocks, 256, 0, stream>>>(
        mm_rp, mm_cv, mashup_tbl, mashup_tbl, INT_MAX,
        d_inv, nullptr, nullptr, 0, nullptr, m1, NM_);
    pull_kernel<3><<<mm_blocks, 256, 0, stream>>>(
        mm_rp, mm_cv, m1, m1, INT_MAX,
        d_inv, mashup_tbl, mashup_tbl, INT_MAX, m1, m2, NM_);

    // ---- attention + prediction tail ----
    attn_pred_kernel<<<B, 512, 0, stream>>>(
        mashup_inputs, service_inputs, member_masked, mask,
        h2, m2,
        att_w1, att_b1, att_w2, att_b2,
        pred_w1, pred_b1, pred_w2, pred_b2,
        (float*)d_out);
}

// Round 3
// 622.358 us; speedup vs baseline: 5.4003x; 1.4540x over previous
//
#include <hip/hip_runtime.h>
#include <climits>

#define NU_ 80000
#define NS_ 20000
#define NM_ 30000
#define UIN_ (NU_ + NS_)
#define DD 128
#define LL 32

// ---------------------------------------------------------------------------
// CSR build: histogram -> multi-block scan -> scatter into packed (col,val)
// ---------------------------------------------------------------------------
__global__ void hist_kernel(const int* __restrict__ rows, int* __restrict__ cnt, int E) {
    int stride = gridDim.x * blockDim.x;
    for (int i = blockIdx.x * blockDim.x + threadIdx.x; i < E; i += stride)
        atomicAdd(&cnt[rows[i]], 1);
}

// pass 1: block b sums cnt[b*1024 .. b*1024+1024) -> bsum[b]
__global__ __launch_bounds__(256) void scan_blocksum(const int* __restrict__ cnt,
                                                     int* __restrict__ bsum, int n) {
    __shared__ int red[256];
    int base = blockIdx.x * 1024 + threadIdx.x * 4;
    int s = 0;
    if (base + 3 < n) {
        int4 v = *reinterpret_cast<const int4*>(cnt + base);
        s = v.x + v.y + v.z + v.w;
    } else {
        for (int i = base; i < n && i < base + 4; ++i) s += cnt[i];
    }
    red[threadIdx.x] = s;
    __syncthreads();
    for (int off = 128; off >= 1; off >>= 1) {
        if (threadIdx.x < off) red[threadIdx.x] += red[threadIdx.x + off];
        __syncthreads();
    }
    if (threadIdx.x == 0) bsum[blockIdx.x] = red[0];
}

// pass 2: block b: offset = sum(bsum[0..b)) + local exclusive scan of its chunk.
// Writes row_ptr and cursor. cursor may alias cnt (each block reads its own
// range before writing it; no cross-block access).
__global__ __launch_bounds__(256) void scan_final(const int* __restrict__ cnt,
                                                  const int* __restrict__ bsum,
                                                  int* __restrict__ row_ptr,
                                                  int* __restrict__ cursor, int n) {
    __shared__ int lds[256];
    __shared__ int blk_off_s;
    const int tid = threadIdx.x;
    const int b   = blockIdx.x;

    int s = 0;
    for (int j = tid; j < b; j += 256) s += bsum[j];
    lds[tid] = s;
    __syncthreads();
    for (int off = 128; off >= 1; off >>= 1) {
        if (tid < off) lds[tid] += lds[tid + off];
        __syncthreads();
    }
    if (tid == 0) blk_off_s = lds[0];
    __syncthreads();
    const int blk_off = blk_off_s;

    int base = b * 1024 + tid * 4;
    int c0 = 0, c1 = 0, c2 = 0, c3 = 0;
    if (base + 3 < n) {
        int4 v = *reinterpret_cast<const int4*>(cnt + base);
        c0 = v.x; c1 = v.y; c2 = v.z; c3 = v.w;
    } else {
        if (base     < n) c0 = cnt[base];
        if (base + 1 < n) c1 = cnt[base + 1];
        if (base + 2 < n) c2 = cnt[base + 2];
        if (base + 3 < n) c3 = cnt[base + 3];
    }
    int tsum = c0 + c1 + c2 + c3;
    __syncthreads();
    lds[tid] = tsum;
    __syncthreads();
    for (int off = 1; off < 256; off <<= 1) {   // inclusive Hillis-Steele
        int v = (tid >= off) ? lds[tid - off] : 0;
        __syncthreads();
        lds[tid] += v;
        __syncthreads();
    }
    int p0 = blk_off + ((tid > 0) ? lds[tid - 1] : 0);
    int p1 = p0 + c0, p2 = p1 + c1, p3 = p2 + c2, p4 = p3 + c3;

    if (base     < n) { row_ptr[base]     = p0; cursor[base]     = p0; if (base     == n - 1) row_ptr[n] = p1; }
    if (base + 1 < n) { row_ptr[base + 1] = p1; cursor[base + 1] = p1; if (base + 1 == n - 1) row_ptr[n] = p2; }
    if (base + 2 < n) { row_ptr[base + 2] = p2; cursor[base + 2] = p2; if (base + 2 == n - 1) row_ptr[n] = p3; }
    if (base + 3 < n) { row_ptr[base + 3] = p3; cursor[base + 3] = p3; if (base + 3 == n - 1) row_ptr[n] = p4; }
}

__global__ void scatter_kernel(const int* __restrict__ rows, const int* __restrict__ cols,
                               const float* __restrict__ vals, int* __restrict__ cursor,
                               uint2* __restrict__ cv, int E) {
    int stride = gridDim.x * blockDim.x;
    for (int i = blockIdx.x * blockDim.x + threadIdx.x; i < E; i += stride) {
        int pos = atomicAdd(&cursor[rows[i]], 1);
        cv[pos] = make_uint2((unsigned)cols[i], __float_as_uint(vals[i]));
    }
}

// ---------------------------------------------------------------------------
// Pull SpMM: one wave per destination row, lane i owns float2 at dim 2i.
// MODE bit0: scale result by d_inv[row]. MODE bit1: out=(orig+hprev+res)/3.
// ---------------------------------------------------------------------------
template <int MODE>
__global__ __launch_bounds__(256) void pull_kernel(
    const int* __restrict__ row_ptr, const uint2* __restrict__ cv,
    const float* __restrict__ xa, const float* __restrict__ xb, int split,
    const float* __restrict__ d_inv,
    const float* __restrict__ oa, const float* __restrict__ ob, int osplit,
    const float* __restrict__ hprev,
    float* __restrict__ out, int n)
{
    const int wid  = (blockIdx.x * blockDim.x + threadIdx.x) >> 6;
    const int lane = threadIdx.x & 63;
    if (wid >= n) return;
    const int beg = row_ptr[wid];
    const int end = row_ptr[wid + 1];

    float2 acc0 = {0.f, 0.f}, acc1 = {0.f, 0.f};
    int e = beg;
    for (; e + 1 < end; e += 2) {
        uint2 p0 = cv[e];
        uint2 p1 = cv[e + 1];
        int   c0 = (int)p0.x;            float v0 = __uint_as_float(p0.y);
        int   c1 = (int)p1.x;            float v1 = __uint_as_float(p1.y);
        const float* x0 = (c0 < split) ? (xa + (size_t)c0 * DD)
                                       : (xb + (size_t)(c0 - split) * DD);
        const float* x1 = (c1 < split) ? (xa + (size_t)c1 * DD)
                                       : (xb + (size_t)(c1 - split) * DD);
        float2 g0 = *reinterpret_cast<const float2*>(x0 + lane * 2);
        float2 g1 = *reinterpret_cast<const float2*>(x1 + lane * 2);
        acc0.x += v0 * g0.x;  acc0.y += v0 * g0.y;
        acc1.x += v1 * g1.x;  acc1.y += v1 * g1.y;
    }
    if (e < end) {
        uint2 p0 = cv[e];
        int   c0 = (int)p0.x;            float v0 = __uint_as_float(p0.y);
        const float* x0 = (c0 < split) ? (xa + (size_t)c0 * DD)
                                       : (xb + (size_t)(c0 - split) * DD);
        float2 g0 = *reinterpret_cast<const float2*>(x0 + lane * 2);
        acc0.x += v0 * g0.x;  acc0.y += v0 * g0.y;
    }
    float2 acc = {acc0.x + acc1.x, acc0.y + acc1.y};

    if (MODE & 1) { float s = d_inv[wid]; acc.x *= s; acc.y *= s; }
    if (MODE & 2) {
        const float inv3 = 1.0f / 3.0f;
        const float* og = (wid < osplit) ? (oa + (size_t)wid * DD)
                                         : (ob + (size_t)(wid - osplit) * DD);
        float2 ov = *reinterpret_cast<const float2*>(og + lane * 2);
        float2 hv = *reinterpret_cast<const float2*>(hprev + (size_t)wid * DD + lane * 2);
        acc.x = (ov.x + hv.x + acc.x) * inv3;
        acc.y = (ov.y + hv.y + acc.y) * inv3;
    }
    *reinterpret_cast<float2*>(out + (size_t)wid * DD + lane * 2) = acc;
}

// ---------------------------------------------------------------------------
// Attention + prediction tail: one block (512 threads) per batch element.
// ---------------------------------------------------------------------------
__global__ __launch_bounds__(512) void attn_pred_kernel(
    const int* __restrict__ mashup_inputs, const int* __restrict__ service_inputs,
    const int* __restrict__ member_masked, const float* __restrict__ mask,
    const float* __restrict__ ui_final,    const float* __restrict__ mash_final,
    const float* __restrict__ att_w1, const float* __restrict__ att_b1,
    const float* __restrict__ att_w2, const float* __restrict__ att_b2,
    const float* __restrict__ pred_w1, const float* __restrict__ pred_b1,
    const float* __restrict__ pred_w2, const float* __restrict__ pred_b2,
    float* __restrict__ out)
{
    const int b   = blockIdx.x;
    const int tid = threadIdx.x;

    __shared__ float mem_lds[LL * 129];
    __shared__ float svc_lds[DD];
    __shared__ float w1_lds[2 * DD * 16];
    __shared__ float hdnw_lds[LL * 16];
    __shared__ float wt_lds[LL];
    __shared__ float new_lds[3 * DD];
    __shared__ float hp_lds[8];
    __shared__ int   midx[LL];

    if (tid < LL) midx[tid] = member_masked[b * LL + tid];
    for (int i = tid; i < 2 * DD * 16; i += 512) w1_lds[i] = att_w1[i];
    if (tid < DD) {
        int sidx = service_inputs[b];
        svc_lds[tid] = ui_final[(size_t)(NU_ + sidx) * DD + tid];
    }
    __syncthreads();

    for (int i = tid; i < LL * DD; i += 512) {
        int l = i >> 7, d = i & 127;
        mem_lds[l * 129 + d] = ui_final[(size_t)midx[l] * DD + d];
    }
    __syncthreads();

    {
        int l = tid >> 4, j = tid & 15;
        float acc = att_b1[j];
        const float* m = &mem_lds[l * 129];
        #pragma unroll 4
        for (int k = 0; k < DD; ++k) acc += m[k] * w1_lds[k * 16 + j];
        #pragma unroll 4
        for (int k = 0; k < DD; ++k) acc += svc_lds[k] * w1_lds[(DD + k) * 16 + j];
        acc = fmaxf(acc, 0.0f);
        hdnw_lds[l * 16 + j] = acc * att_w2[j];
    }
    __syncthreads();

    if (tid < 64) {
        float s = -3.0e38f;
        if (tid < LL) {
            s = att_b2[0];
            for (int j = 0; j < 16; ++j) s += hdnw_lds[tid * 16 + j];
            if (mask[b * LL + tid] > 0.0f) s = -1.0e9f;
        }
        float mx = s;
        for (int off = 16; off >= 1; off >>= 1) mx = fmaxf(mx, __shfl_xor(mx, off));
        float ex = (tid < LL) ? __expf(s - mx) : 0.0f;
        float sum = ex;
        for (int off = 16; off >= 1; off >>= 1) sum += __shfl_xor(sum, off);
        if (tid < LL) wt_lds[tid] = ex / sum;
    }
    __syncthreads();

    if (tid < DD) {
        float g = 0.0f;
        #pragma unroll 4
        for (int l = 0; l < LL; ++l) g += wt_lds[l] * mem_lds[l * 129 + tid];
        int   mi = mashup_inputs[b];
        float me = g + mash_final[(size_t)mi * DD + tid];
        float sv = svc_lds[tid];
        new_lds[tid]          = me * sv;
        new_lds[DD + tid]     = me;
        new_lds[2 * DD + tid] = sv;
    }
    __syncthreads();

    if (tid < 8) {
        float acc = pred_b1[tid];
        for (int k = 0; k < 3 * DD; ++k) acc += new_lds[k] * pred_w1[k * 8 + tid];
        acc = fmaxf(acc, 0.0f);
        hp_lds[tid] = acc * pred_w2[tid];
    }
    __syncthreads();

    if (tid == 0) {
        float z = pred_b2[0];
        for (int j = 0; j < 8; ++j) z += hp_lds[j];
        out[b] = 1.0f / (1.0f + __expf(-z));
    }
}

// ---------------------------------------------------------------------------
extern "C" void kernel_launch(void* const* d_in, const int* in_sizes, int n_in,
                              void* d_out, int out_size, void* d_ws, size_t ws_size,
                              hipStream_t stream) {
    const int*   mashup_inputs  = (const int*)  d_in[0];
    const int*   service_inputs = (const int*)  d_in[1];
    const int*   member_masked  = (const int*)  d_in[2];
    const float* mask           = (const float*)d_in[3];
    const int*   adj_rows       = (const int*)  d_in[4];
    const int*   adj_cols       = (const int*)  d_in[5];
    const float* adj_vals       = (const float*)d_in[6];
    const int*   A_rows         = (const int*)  d_in[7];
    const int*   A_cols         = (const int*)  d_in[8];
    const float* A_vals         = (const float*)d_in[9];
    const float* d_inv          = (const float*)d_in[10];
    const float* user_tbl       = (const float*)d_in[11];
    const float* service_tbl    = (const float*)d_in[12];
    const float* mashup_tbl     = (const float*)d_in[13];
    const float* att_w1         = (const float*)d_in[14];
    const float* att_b1         = (const float*)d_in[15];
    const float* att_w2         = (const float*)d_in[16];
    const float* att_b2         = (const float*)d_in[17];
    const float* pred_w1        = (const float*)d_in[18];
    const float* pred_b1        = (const float*)d_in[19];
    const float* pred_w2        = (const float*)d_in[20];
    const float* pred_b2        = (const float*)d_in[21];

    const int E_ui = in_sizes[4];
    const int E_mm = in_sizes[7];
    const int B    = in_sizes[0];

    const int UI_RP_SZ = 100004;   // UIN_+1 padded to keep 16B alignment
    const int MM_RP_SZ = 30004;    // NM_+1 padded
    const int NB_UI = (UIN_ + 1023) / 1024;   // 98
    const int NB_MM = (NM_  + 1023) / 1024;   // 30

    // ---- workspace layout ----
    float* ws = (float*)d_ws;
    float* h1 = ws;                               // UIN*128
    float* h2 = h1 + (size_t)UIN_ * DD;           // UIN*128  (ui_final)
    float* m1 = h2 + (size_t)UIN_ * DD;           // NM*128
    float* m2 = m1 + (size_t)NM_ * DD;            // NM*128   (mash_final)
    uint2* ui_cv = (uint2*)(m2 + (size_t)NM_ * DD);           // E_ui
    uint2* mm_cv = ui_cv + E_ui;                              // E_mm
    int*   ui_rp = (int*)(mm_cv + E_mm);          // UI_RP_SZ (16B-aligned)
    int*   ui_cc = ui_rp + UI_RP_SZ;              // UI_RP_SZ (16B-aligned)
    int*   mm_rp = ui_cc + UI_RP_SZ;              // MM_RP_SZ
    int*   mm_cc = mm_rp + MM_RP_SZ;              // MM_RP_SZ
    int*   ui_bs = mm_cc + MM_RP_SZ;              // NB_UI block sums
    int*   mm_bs = ui_bs + NB_UI;                 // NB_MM block sums

    // ---- CSR build (both graphs) ----
    hipMemsetAsync(ui_cc, 0, UI_RP_SZ * sizeof(int), stream);
    hipMemsetAsync(mm_cc, 0, MM_RP_SZ * sizeof(int), stream);
    hist_kernel<<<1024, 256, 0, stream>>>(adj_rows, ui_cc, E_ui);
    hist_kernel<<<512, 256, 0, stream>>>(A_rows, mm_cc, E_mm);
    scan_blocksum<<<NB_UI, 256, 0, stream>>>(ui_cc, ui_bs, UIN_);
    scan_blocksum<<<NB_MM, 256, 0, stream>>>(mm_cc, mm_bs, NM_);
    scan_final<<<NB_UI, 256, 0, stream>>>(ui_cc, ui_bs, ui_rp, ui_cc, UIN_);
    scan_final<<<NB_MM, 256, 0, stream>>>(mm_cc, mm_bs, mm_rp, mm_cc, NM_);
    scatter_kernel<<<1024, 256, 0, stream>>>(adj_rows, adj_cols, adj_vals, ui_cc, ui_cv, E_ui);
    scatter_kernel<<<512, 256, 0, stream>>>(A_rows, A_cols, A_vals, mm_cc, mm_cv, E_mm);

    // ---- user/service LightGCN propagation (2 layers, pull) ----
    const int ui_blocks = (UIN_ + 3) / 4;   // 4 waves/block, 1 wave/row
    pull_kernel<0><<<ui_blocks, 256, 0, stream>>>(
        ui_rp, ui_cv, user_tbl, service_tbl, NU_,
        nullptr, nullptr, nullptr, 0, nullptr, h1, UIN_);
    pull_kernel<2><<<ui_blocks, 256, 0, stream>>>(
        ui_rp, ui_cv, h1, h1, INT_MAX,
        nullptr, user_tbl, service_tbl, NU_, h1, h2, UIN_);

    // ---- mashup propagation (2 layers, pull, d_inv fused) ----
    const int mm_blocks = (NM_ + 3) / 4;
    pull_kernel<1><<<mm_blocks, 256, 0, stream>>>(
        mm_rp, mm_cv, mashup_tbl, mashup_tbl, INT_MAX,
        d_inv, nullptr, nullptr, 0, nullptr, m1, NM_);
    pull_kernel<3><<<mm_blocks, 256, 0, stream>>>(
        mm_rp, mm_cv, m1, m1, INT_MAX,
        d_inv, mashup_tbl, mashup_tbl, INT_MAX, m1, m2, NM_);

    // ---- attention + prediction tail ----
    attn_pred_kernel<<<B, 512, 0, stream>>>(
        mashup_inputs, service_inputs, member_masked, mask,
        h2, m2,
        att_w1, att_b1, att_w2, att_b2,
        pred_w1, pred_b1, pred_w2, pred_b2,
        (float*)d_out);
}

// Round 4
// 531.230 us; speedup vs baseline: 6.3267x; 1.1715x over previous
//
#include <hip/hip_runtime.h>
#include <climits>

#define NU_ 80000
#define NS_ 20000
#define NM_ 30000
#define UIN_ (NU_ + NS_)
#define DD 128
#define LL 32

typedef unsigned int  uint32;
typedef unsigned short ushort16;

__device__ __forceinline__ float bflo(uint32 u) { return __uint_as_float(u << 16); }
__device__ __forceinline__ float bfhi(uint32 u) { return __uint_as_float(u & 0xffff0000u); }
__device__ __forceinline__ ushort16 f2bf(float f) {
    uint32 u = __float_as_uint(f);
    return (ushort16)((u + 0x7fffu + ((u >> 16) & 1u)) >> 16);   // RNE
}
__device__ __forceinline__ uint32 pack2bf(float lo, float hi) {
    return (uint32)f2bf(lo) | ((uint32)f2bf(hi) << 16);
}

// ---------------------------------------------------------------------------
// fp32 (split tables) -> packed bf16 table. n2 = total element pairs.
// ---------------------------------------------------------------------------
__global__ void convert_kernel(const float* __restrict__ srcA, const float* __restrict__ srcB,
                               int split_rows, uint32* __restrict__ dst, size_t n2) {
    size_t stride = (size_t)gridDim.x * blockDim.x;
    const size_t split_e = (size_t)split_rows * DD;
    for (size_t i = (size_t)blockIdx.x * blockDim.x + threadIdx.x; i < n2; i += stride) {
        size_t e = i * 2;
        const float* s = (e < split_e) ? (srcA + e) : (srcB + (e - split_e));
        float2 v = *reinterpret_cast<const float2*>(s);
        dst[i] = pack2bf(v.x, v.y);
    }
}

// ---------------------------------------------------------------------------
// CSR build: histogram -> multi-block scan -> scatter into packed (col,val)
// ---------------------------------------------------------------------------
__global__ void hist_kernel(const int* __restrict__ rows, int* __restrict__ cnt, int E) {
    int stride = gridDim.x * blockDim.x;
    for (int i = blockIdx.x * blockDim.x + threadIdx.x; i < E; i += stride)
        atomicAdd(&cnt[rows[i]], 1);
}

__global__ __launch_bounds__(256) void scan_blocksum(const int* __restrict__ cnt,
                                                     int* __restrict__ bsum, int n) {
    __shared__ int red[256];
    int base = blockIdx.x * 1024 + threadIdx.x * 4;
    int s = 0;
    if (base + 3 < n) {
        int4 v = *reinterpret_cast<const int4*>(cnt + base);
        s = v.x + v.y + v.z + v.w;
    } else {
        for (int i = base; i < n && i < base + 4; ++i) s += cnt[i];
    }
    red[threadIdx.x] = s;
    __syncthreads();
    for (int off = 128; off >= 1; off >>= 1) {
        if (threadIdx.x < off) red[threadIdx.x] += red[threadIdx.x + off];
        __syncthreads();
    }
    if (threadIdx.x == 0) bsum[blockIdx.x] = red[0];
}

__global__ __launch_bounds__(256) void scan_final(const int* __restrict__ cnt,
                                                  const int* __restrict__ bsum,
                                                  int* __restrict__ row_ptr,
                                                  int* __restrict__ cursor, int n) {
    __shared__ int lds[256];
    __shared__ int blk_off_s;
    const int tid = threadIdx.x;
    const int b   = blockIdx.x;

    int s = 0;
    for (int j = tid; j < b; j += 256) s += bsum[j];
    lds[tid] = s;
    __syncthreads();
    for (int off = 128; off >= 1; off >>= 1) {
        if (tid < off) lds[tid] += lds[tid + off];
        __syncthreads();
    }
    if (tid == 0) blk_off_s = lds[0];
    __syncthreads();
    const int blk_off = blk_off_s;

    int base = b * 1024 + tid * 4;
    int c0 = 0, c1 = 0, c2 = 0, c3 = 0;
    if (base + 3 < n) {
        int4 v = *reinterpret_cast<const int4*>(cnt + base);
        c0 = v.x; c1 = v.y; c2 = v.z; c3 = v.w;
    } else {
        if (base     < n) c0 = cnt[base];
        if (base + 1 < n) c1 = cnt[base + 1];
        if (base + 2 < n) c2 = cnt[base + 2];
        if (base + 3 < n) c3 = cnt[base + 3];
    }
    int tsum = c0 + c1 + c2 + c3;
    __syncthreads();
    lds[tid] = tsum;
    __syncthreads();
    for (int off = 1; off < 256; off <<= 1) {
        int v = (tid >= off) ? lds[tid - off] : 0;
        __syncthreads();
        lds[tid] += v;
        __syncthreads();
    }
    int p0 = blk_off + ((tid > 0) ? lds[tid - 1] : 0);
    int p1 = p0 + c0, p2 = p1 + c1, p3 = p2 + c2, p4 = p3 + c3;

    if (base     < n) { row_ptr[base]     = p0; cursor[base]     = p0; if (base     == n - 1) row_ptr[n] = p1; }
    if (base + 1 < n) { row_ptr[base + 1] = p1; cursor[base + 1] = p1; if (base + 1 == n - 1) row_ptr[n] = p2; }
    if (base + 2 < n) { row_ptr[base + 2] = p2; cursor[base + 2] = p2; if (base + 2 == n - 1) row_ptr[n] = p3; }
    if (base + 3 < n) { row_ptr[base + 3] = p3; cursor[base + 3] = p3; if (base + 3 == n - 1) row_ptr[n] = p4; }
}

__global__ void scatter_kernel(const int* __restrict__ rows, const int* __restrict__ cols,
                               const float* __restrict__ vals, int* __restrict__ cursor,
                               uint2* __restrict__ cv, int E) {
    int stride = gridDim.x * blockDim.x;
    for (int i = blockIdx.x * blockDim.x + threadIdx.x; i < E; i += stride) {
        int pos = atomicAdd(&cursor[rows[i]], 1);
        cv[pos] = make_uint2((unsigned)cols[i], __float_as_uint(vals[i]));
    }
}

// ---------------------------------------------------------------------------
// Pull SpMM (bf16 tables): one wave per destination row, lane owns dims 2l,2l+1.
// MODE bit0: scale by d_inv[row]. MODE bit1: out=(orig+hprev+res)/3.
// ---------------------------------------------------------------------------
template <int MODE>
__global__ __launch_bounds__(256) void pull_kernel(
    const int* __restrict__ row_ptr, const uint2* __restrict__ cv,
    const ushort16* __restrict__ x,
    const float* __restrict__ d_inv,
    const ushort16* __restrict__ orig, const ushort16* __restrict__ hprev,
    ushort16* __restrict__ out, int n)
{
    const int wid  = (blockIdx.x * blockDim.x + threadIdx.x) >> 6;
    const int lane = threadIdx.x & 63;
    if (wid >= n) return;
    const int beg = row_ptr[wid];
    const int end = row_ptr[wid + 1];

    float ax0 = 0.f, ay0 = 0.f, ax1 = 0.f, ay1 = 0.f;
    float ax2 = 0.f, ay2 = 0.f, ax3 = 0.f, ay3 = 0.f;
    int e = beg;
    for (; e + 3 < end; e += 4) {
        uint2 p0 = cv[e],     p1 = cv[e + 1];
        uint2 p2 = cv[e + 2], p3 = cv[e + 3];
        uint32 g0 = *reinterpret_cast<const uint32*>(x + (((size_t)p0.x) << 7) + lane * 2);
        uint32 g1 = *reinterpret_cast<const uint32*>(x + (((size_t)p1.x) << 7) + lane * 2);
        uint32 g2 = *reinterpret_cast<const uint32*>(x + (((size_t)p2.x) << 7) + lane * 2);
        uint32 g3 = *reinterpret_cast<const uint32*>(x + (((size_t)p3.x) << 7) + lane * 2);
        float v0 = __uint_as_float(p0.y), v1 = __uint_as_float(p1.y);
        float v2 = __uint_as_float(p2.y), v3 = __uint_as_float(p3.y);
        ax0 += v0 * bflo(g0); ay0 += v0 * bfhi(g0);
        ax1 += v1 * bflo(g1); ay1 += v1 * bfhi(g1);
        ax2 += v2 * bflo(g2); ay2 += v2 * bfhi(g2);
        ax3 += v3 * bflo(g3); ay3 += v3 * bfhi(g3);
    }
    for (; e < end; ++e) {
        uint2 p0 = cv[e];
        uint32 g0 = *reinterpret_cast<const uint32*>(x + (((size_t)p0.x) << 7) + lane * 2);
        float v0 = __uint_as_float(p0.y);
        ax0 += v0 * bflo(g0); ay0 += v0 * bfhi(g0);
    }
    float accx = (ax0 + ax1) + (ax2 + ax3);
    float accy = (ay0 + ay1) + (ay2 + ay3);

    if (MODE & 1) { float s = d_inv[wid]; accx *= s; accy *= s; }
    if (MODE & 2) {
        const float inv3 = 1.0f / 3.0f;
        uint32 o = *reinterpret_cast<const uint32*>(orig  + (((size_t)wid) << 7) + lane * 2);
        uint32 h = *reinterpret_cast<const uint32*>(hprev + (((size_t)wid) << 7) + lane * 2);
        accx = (bflo(o) + bflo(h) + accx) * inv3;
        accy = (bfhi(o) + bfhi(h) + accy) * inv3;
    }
    *reinterpret_cast<uint32*>(out + (((size_t)wid) << 7) + lane * 2) = pack2bf(accx, accy);
}

// ---------------------------------------------------------------------------
// Attention + prediction tail: one block (512 threads) per batch element.
// ui_final / mash_final are bf16 tables.
// ---------------------------------------------------------------------------
__global__ __launch_bounds__(512) void attn_pred_kernel(
    const int* __restrict__ mashup_inputs, const int* __restrict__ service_inputs,
    const int* __restrict__ member_masked, const float* __restrict__ mask,
    const ushort16* __restrict__ ui_final, const ushort16* __restrict__ mash_final,
    const float* __restrict__ att_w1, const float* __restrict__ att_b1,
    const float* __restrict__ att_w2, const float* __restrict__ att_b2,
    const float* __restrict__ pred_w1, const float* __restrict__ pred_b1,
    const float* __restrict__ pred_w2, const float* __restrict__ pred_b2,
    float* __restrict__ out)
{
    const int b   = blockIdx.x;
    const int tid = threadIdx.x;

    __shared__ float mem_lds[LL * 129];
    __shared__ float svc_lds[DD];
    __shared__ float mash_lds[DD];
    __shared__ float w1_lds[2 * DD * 16];
    __shared__ float hdnw_lds[LL * 16];
    __shared__ float wt_lds[LL];
    __shared__ float new_lds[3 * DD];
    __shared__ float hp_lds[8];
    __shared__ int   midx[LL];

    if (tid < LL) midx[tid] = member_masked[b * LL + tid];
    for (int i = tid; i < 2 * DD * 16; i += 512) w1_lds[i] = att_w1[i];
    if (tid < 64) {
        int sidx = service_inputs[b];
        uint32 u = *reinterpret_cast<const uint32*>(ui_final + (size_t)(NU_ + sidx) * DD + tid * 2);
        svc_lds[tid * 2]     = bflo(u);
        svc_lds[tid * 2 + 1] = bfhi(u);
    } else if (tid >= 448) {   // lanes 448..511 load the mashup row
        int t  = tid - 448;
        int mi = mashup_inputs[b];
        uint32 u = *reinterpret_cast<const uint32*>(mash_final + (size_t)mi * DD + t * 2);
        mash_lds[t * 2]     = bflo(u);
        mash_lds[t * 2 + 1] = bfhi(u);
    }
    __syncthreads();

    for (int i = tid; i < LL * 64; i += 512) {
        int l = i >> 6, dp = (i & 63) * 2;
        uint32 u = *reinterpret_cast<const uint32*>(ui_final + (size_t)midx[l] * DD + dp);
        mem_lds[l * 129 + dp]     = bflo(u);
        mem_lds[l * 129 + dp + 1] = bfhi(u);
    }
    __syncthreads();

    {
        int l = tid >> 4, j = tid & 15;
        float acc = att_b1[j];
        const float* m = &mem_lds[l * 129];
        #pragma unroll 4
        for (int k = 0; k < DD; ++k) acc += m[k] * w1_lds[k * 16 + j];
        #pragma unroll 4
        for (int k = 0; k < DD; ++k) acc += svc_lds[k] * w1_lds[(DD + k) * 16 + j];
        acc = fmaxf(acc, 0.0f);
        hdnw_lds[l * 16 + j] = acc * att_w2[j];
    }
    __syncthreads();

    if (tid < 64) {
        float s = -3.0e38f;
        if (tid < LL) {
            s = att_b2[0];
            for (int j = 0; j < 16; ++j) s += hdnw_lds[tid * 16 + j];
            if (mask[b * LL + tid] > 0.0f) s = -1.0e9f;
        }
        float mx = s;
        for (int off = 16; off >= 1; off >>= 1) mx = fmaxf(mx, __shfl_xor(mx, off));
        float ex = (tid < LL) ? __expf(s - mx) : 0.0f;
        float sum = ex;
        for (int off = 16; off >= 1; off >>= 1) sum += __shfl_xor(sum, off);
        if (tid < LL) wt_lds[tid] = ex / sum;
    }
    __syncthreads();

    if (tid < DD) {
        float g = 0.0f;
        #pragma unroll 4
        for (int l = 0; l < LL; ++l) g += wt_lds[l] * mem_lds[l * 129 + tid];
        float me = g + mash_lds[tid];
        float sv = svc_lds[tid];
        new_lds[tid]          = me * sv;
        new_lds[DD + tid]     = me;
        new_lds[2 * DD + tid] = sv;
    }
    __syncthreads();

    if (tid < 8) {
        float acc = pred_b1[tid];
        for (int k = 0; k < 3 * DD; ++k) acc += new_lds[k] * pred_w1[k * 8 + tid];
        acc = fmaxf(acc, 0.0f);
        hp_lds[tid] = acc * pred_w2[tid];
    }
    __syncthreads();

    if (tid == 0) {
        float z = pred_b2[0];
        for (int j = 0; j < 8; ++j) z += hp_lds[j];
        out[b] = 1.0f / (1.0f + __expf(-z));
    }
}

// ---------------------------------------------------------------------------
extern "C" void kernel_launch(void* const* d_in, const int* in_sizes, int n_in,
                              void* d_out, int out_size, void* d_ws, size_t ws_size,
                              hipStream_t stream) {
    const int*   mashup_inputs  = (const int*)  d_in[0];
    const int*   service_inputs = (const int*)  d_in[1];
    const int*   member_masked  = (const int*)  d_in[2];
    const float* mask           = (const float*)d_in[3];
    const int*   adj_rows       = (const int*)  d_in[4];
    const int*   adj_cols       = (const int*)  d_in[5];
    const float* adj_vals       = (const float*)d_in[6];
    const int*   A_rows         = (const int*)  d_in[7];
    const int*   A_cols         = (const int*)  d_in[8];
    const float* A_vals         = (const float*)d_in[9];
    const float* d_inv          = (const float*)d_in[10];
    const float* user_tbl       = (const float*)d_in[11];
    const float* service_tbl    = (const float*)d_in[12];
    const float* mashup_tbl     = (const float*)d_in[13];
    const float* att_w1         = (const float*)d_in[14];
    const float* att_b1         = (const float*)d_in[15];
    const float* att_w2         = (const float*)d_in[16];
    const float* att_b2         = (const float*)d_in[17];
    const float* pred_w1        = (const float*)d_in[18];
    const float* pred_b1        = (const float*)d_in[19];
    const float* pred_w2        = (const float*)d_in[20];
    const float* pred_b2        = (const float*)d_in[21];

    const int E_ui = in_sizes[4];
    const int E_mm = in_sizes[7];
    const int B    = in_sizes[0];

    const int UI_RP_SZ = 100004;
    const int MM_RP_SZ = 30004;
    const int NB_UI = (UIN_ + 1023) / 1024;   // 98
    const int NB_MM = (NM_  + 1023) / 1024;   // 30

    // ---- workspace layout ----
    uint2*    ui_cv   = (uint2*)d_ws;                          // E_ui
    uint2*    mm_cv   = ui_cv + E_ui;                          // E_mm
    int*      ui_rp   = (int*)(mm_cv + E_mm);                  // UI_RP_SZ
    int*      ui_cc   = ui_rp + UI_RP_SZ;
    int*      mm_rp   = ui_cc + UI_RP_SZ;
    int*      mm_cc   = mm_rp + MM_RP_SZ;
    int*      ui_bs   = mm_cc + MM_RP_SZ;                      // NB_UI
    int*      mm_bs   = ui_bs + NB_UI;                         // NB_MM (98+30=128, aligned)
    ushort16* ui_bf   = (ushort16*)(mm_bs + NB_MM);            // UIN*128
    ushort16* h1      = ui_bf + (size_t)UIN_ * DD;             // UIN*128
    ushort16* h2      = h1    + (size_t)UIN_ * DD;             // UIN*128 (ui_final)
    ushort16* mash_bf = h2    + (size_t)UIN_ * DD;             // NM*128
    ushort16* m1      = mash_bf + (size_t)NM_ * DD;            // NM*128
    ushort16* m2      = m1    + (size_t)NM_ * DD;              // NM*128 (mash_final)

    // ---- bf16 conversion of base tables ----
    convert_kernel<<<2048, 256, 0, stream>>>(user_tbl, service_tbl, NU_,
                                             (uint32*)ui_bf, (size_t)UIN_ * DD / 2);
    convert_kernel<<<1024, 256, 0, stream>>>(mashup_tbl, mashup_tbl, NM_,
                                             (uint32*)mash_bf, (size_t)NM_ * DD / 2);

    // ---- CSR build (both graphs) ----
    hipMemsetAsync(ui_cc, 0, UI_RP_SZ * sizeof(int), stream);
    hipMemsetAsync(mm_cc, 0, MM_RP_SZ * sizeof(int), stream);
    hist_kernel<<<1024, 256, 0, stream>>>(adj_rows, ui_cc, E_ui);
    hist_kernel<<<512, 256, 0, stream>>>(A_rows, mm_cc, E_mm);
    scan_blocksum<<<NB_UI, 256, 0, stream>>>(ui_cc, ui_bs, UIN_);
    scan_blocksum<<<NB_MM, 256, 0, stream>>>(mm_cc, mm_bs, NM_);
    scan_final<<<NB_UI, 256, 0, stream>>>(ui_cc, ui_bs, ui_rp, ui_cc, UIN_);
    scan_final<<<NB_MM, 256, 0, stream>>>(mm_cc, mm_bs, mm_rp, mm_cc, NM_);
    scatter_kernel<<<1024, 256, 0, stream>>>(adj_rows, adj_cols, adj_vals, ui_cc, ui_cv, E_ui);
    scatter_kernel<<<512, 256, 0, stream>>>(A_rows, A_cols, A_vals, mm_cc, mm_cv, E_mm);

    // ---- user/service LightGCN propagation (2 layers, pull, bf16) ----
    const int ui_blocks = (UIN_ + 3) / 4;
    pull_kernel<0><<<ui_blocks, 256, 0, stream>>>(
        ui_rp, ui_cv, ui_bf, nullptr, nullptr, nullptr, h1, UIN_);
    pull_kernel<2><<<ui_blocks, 256, 0, stream>>>(
        ui_rp, ui_cv, h1, nullptr, ui_bf, h1, h2, UIN_);

    // ---- mashup propagation (2 layers, pull, d_inv fused, bf16) ----
    const int mm_blocks = (NM_ + 3) / 4;
    pull_kernel<1><<<mm_blocks, 256, 0, stream>>>(
        mm_rp, mm_cv, mash_bf, d_inv, nullptr, nullptr, m1, NM_);
    pull_kernel<3><<<mm_blocks, 256, 0, stream>>>(
        mm_rp, mm_cv, m1, d_inv, mash_bf, m1, m2, NM_);

    // ---- attention + prediction tail ----
    attn_pred_kernel<<<B, 512, 0, stream>>>(
        mashup_inputs, service_inputs, member_masked, mask,
        h2, m2,
        att_w1, att_b1, att_w2, att_b2,
        pred_w1, pred_b1, pred_w2, pred_b2,
        (float*)d_out);
}